// Round 3
// baseline (533.121 us; speedup 1.0000x reference)
//
#include <hip/hip_runtime.h>
#include <hip/hip_bf16.h>
#include <stdint.h>

typedef __bf16 bf16_t;
typedef bf16_t bf16x8 __attribute__((ext_vector_type(8)));
typedef bf16_t bf16x4 __attribute__((ext_vector_type(4)));
typedef float  f32x4  __attribute__((ext_vector_type(4)));

#define B_  16
#define S_  1024
#define D_  1024
#define BS_ (B_ * S_)            // 16384
#define MAT_ (S_ * D_)           // 1048576 elems per batch matrix

#define BAR()   __builtin_amdgcn_s_barrier()
#define VMC4()  asm volatile("s_waitcnt vmcnt(4)" ::: "memory")
#define SBAR0() __builtin_amdgcn_sched_barrier(0)
#define PRIO1() __builtin_amdgcn_s_setprio(1)
#define PRIO0() __builtin_amdgcn_s_setprio(0)

__device__ __forceinline__ void async_load16(const void* g, void* l) {
    __builtin_amdgcn_global_load_lds((__attribute__((address_space(1))) void*)(g),
                                     (__attribute__((address_space(3))) void*)(l),
                                     16, 0, 0);
}

// ---------------------------------------------------------------------------
// 256x256 8-phase pipelined GEMM (HK/m201 schedule in plain HIP).
// C[m,n] = sum_k A[m,k]*B[n,k]   (B given K-contiguous / transposed)
// SPLIT=0: plain bf16, BK=64, (row&7)<<4 LDS XOR-swizzle (conflict-free).
// SPLIT=1: 3-term Markidis hi/lo bf16, BK=32, ((row>>1)&3)<<4 swizzle.
// OSP=1: C written as bf16 hi/lo pair.
// XS=1: batch-per-XCD remap, grid (4,4,16).
// XS=2: PAIRED mode, grid (4,4,16): each block runs GEMM-0 (gAh,gBh)->Cf
//       then GEMM-1 (gAl,gBl)->Cf+16*MAT_ back-to-back (no block restart).
// XS=3: G1 mode, grid (4,64,1): 8 contiguous bm per XCD (A-panel L2 reuse).
// STATS=1: epilogue emits per-block softmax partials for both axes.
//
// Scheduling notes (round-3):
//  - NO explicit lgkmcnt(0): ds_reads are plain loads, the compiler inserts
//    fine-grained counted lgkm waits before each consuming MFMA, so the MFMA
//    cluster starts while tail reads are still in flight.
//  - sched_barrier(0) after each MFMA cluster pins it before the closing
//    s_barrier (no MFMA/wait can sink across the phase fence) -> all reads
//    of a phase complete before any wave can issue next-phase LDS writes.
//  - vmcnt(4) (asm, "memory") at phases 4/8 only: 2 loads/half-tile, 2
//    half-tiles allowed in flight; its compiler-fence also stops ds_reads
//    hoisting above the buffer-swap barrier.  Tail stages clamp to NT-1.
//  - Swizzle is both-sides (rule 21): linear LDS dest, pre-permuted global
//    source chunk, XOR'd ds_read address (same involution).
// ---------------------------------------------------------------------------
template <int SPLIT, int OSP, int XS, int STATS>
__global__ __launch_bounds__(512, 2)
void gemm8p(const bf16_t* __restrict__ gAh, const bf16_t* __restrict__ gAl,
            const bf16_t* __restrict__ gBh, const bf16_t* __restrict__ gBl,
            float* __restrict__ Cf, bf16_t* __restrict__ Ch, bf16_t* __restrict__ Cl,
            float* __restrict__ Mp2, float* __restrict__ Zp2,
            float* __restrict__ Np2, float* __restrict__ Yp2,
            int M, int N, int K, long sA, long sB, long sC)
{
    (void)M;
    constexpr int BK  = SPLIT ? 32 : 64;
    constexpr int BUF = 65536;
    __shared__ __attribute__((aligned(16))) char smem[2 * BUF];   // 128 KiB

    const int tid  = threadIdx.x;
    const int w    = tid >> 6;
    const int lane = tid & 63;
    const int wm   = w >> 2;            // 0..1  (row half)
    const int wn   = w & 3;             // 0..3  (col quarter)
    const int fm   = lane & 15;
    const int quad = lane >> 4;

    int bm, bn, b;
    if constexpr (XS == 1 || XS == 2) {
        // batch-per-XCD: XCD k owns batches {2k,2k+1} (bijective on 4x4x16)
        const int flat = (int)blockIdx.x + ((int)blockIdx.y << 2) + ((int)blockIdx.z << 4);
        const int xcd = flat & 7, slot = flat >> 3;
        b  = (xcd << 1) | (slot >> 4);
        bm = (slot >> 2) & 3;
        bn = slot & 3;
    } else if constexpr (XS == 3) {
        // grid (4,64,1): XCD k owns bm in [8k,8k+8) (A-panel reuse in L2)
        const int flat = (int)blockIdx.x + ((int)blockIdx.y << 2);
        const int xcd = flat & 7, slot = flat >> 3;      // slot in [0,32)
        b  = 0;
        bm = (xcd << 3) | (slot >> 2);
        bn = slot & 3;
    } else {
        bn = blockIdx.x; bm = blockIdx.y; b = blockIdx.z;
    }

    const int NT    = K / BK;
    const int abase = (int)((long)b * sA) + bm * 256 * K;
    const int bbase = (int)((long)b * sB) + bn * 256 * K;

    // ---- per-thread stage offsets (global elem offset sans k; lds byte) ----
    int aof[2][2], bof[2][2], lof[2][2];
    if constexpr (!SPLIT) {
        // component tile [256][64] bf16 (128B rows). Linear LDS dest o;
        // source 16B-chunk permuted by (row&7) so read-side XOR matches.
#pragma unroll
        for (int h = 0; h < 2; ++h)
#pragma unroll
            for (int i = 0; i < 2; ++i) {
                const int o   = h * 16384 + i * 8192 + tid * 16;
                const int row = o >> 7;
                const int c   = ((o >> 4) & 7) ^ (row & 7);
                aof[h][i] = abase + row * K + c * 8;
                bof[h][i] = bbase + row * K + c * 8;
                lof[h][i] = o;
            }
    } else {
        // component tile [256][32] bf16 (64B rows): chunk ^= (row>>1)&3.
#pragma unroll
        for (int h = 0; h < 2; ++h) {
            const int o   = h * 8192 + tid * 16;
            const int row = o >> 6;
            const int c   = ((o >> 4) & 3) ^ ((row >> 1) & 3);
            aof[h][0] = abase + row * K + c * 8;
            bof[h][0] = bbase + row * K + c * 8;
            lof[h][0] = o;
        }
    }

    f32x4 acc[8][4] = {};

    if constexpr (!SPLIT) {
        // =================== plain bf16, BK=64 ===================
        constexpr int NHALF = (XS == 2) ? 2 : 1;
        const bf16_t* pA = gAh;
        const bf16_t* pB = gBh;

        auto stgA = [&](int t, int h, int lb) {
            const int k = (t < NT ? t : NT - 1) * BK;
            async_load16(pA + (aof[h][0] + k), smem + lb + lof[h][0]);
            async_load16(pA + (aof[h][1] + k), smem + lb + lof[h][1]);
        };
        auto stgB = [&](int t, int h, int lb) {
            const int k = (t < NT ? t : NT - 1) * BK;
            async_load16(pB + (bof[h][0] + k), smem + lb + 32768 + lof[h][0]);
            async_load16(pB + (bof[h][1] + k), smem + lb + 32768 + lof[h][1]);
        };
        const int xb = (fm & 7) << 4;              // read-side XOR = (row&7)<<4
        auto ldA = [&](int lb, int m, int ks) -> bf16x8 {
            const int row = wm * 128 + m * 16 + fm;
            return *(const bf16x8*)(smem + lb + row * 128 + ((ks * 64 + quad * 16) ^ xb));
        };
        auto ldB = [&](int lb, int n, int ks) -> bf16x8 {
            const int row = wn * 64 + n * 16 + fm;
            return *(const bf16x8*)(smem + lb + 32768 + row * 128 + ((ks * 64 + quad * 16) ^ xb));
        };

        bf16x8 ar[4][2], br[4][2];
        auto qp = [&](int mh, int nh) {
#pragma unroll
            for (int m = 0; m < 4; ++m)
#pragma unroll
                for (int n = 0; n < 2; ++n) {
                    f32x4 c = acc[mh * 4 + m][nh * 2 + n];
                    c = __builtin_amdgcn_mfma_f32_16x16x32_bf16(ar[m][0], br[nh * 2 + n][0], c, 0, 0, 0);
                    c = __builtin_amdgcn_mfma_f32_16x16x32_bf16(ar[m][1], br[nh * 2 + n][1], c, 0, 0, 0);
                    acc[mh * 4 + m][nh * 2 + n] = c;
                }
        };

        for (int half = 0; half < NHALF; ++half) {
            if constexpr (XS == 2) {
                pA = half ? gAl : gAh;
                pB = half ? gBl : gBh;
            }
            float* Cfp = Cf + (half ? (long)B_ * MAT_ : 0);
#pragma unroll
            for (int i = 0; i < 8; ++i)
#pragma unroll
                for (int j = 0; j < 4; ++j) acc[i][j] = f32x4{0.f, 0.f, 0.f, 0.f};

            // prologue: tile0 full + tile1 B; vmcnt(4) => tile0 resident
            // (also drains previous half's C-stores and tail stages)
            stgA(0, 0, 0); stgA(0, 1, 0); stgB(0, 0, 0); stgB(0, 1, 0);
            stgB(1, 0, BUF); stgB(1, 1, BUF);
            VMC4(); BAR();

            const int NIT = NT >> 1;
            for (int it = 0; it < NIT; ++it) {
                const int t = it << 1;
#pragma unroll
                for (int ph = 0; ph < 2; ++ph) {
                    const int rb = ph ? BUF : 0;
                    const int ob = ph ? 0 : BUF;
                    const int tt = t + ph;
                    // P1
                    stgA(tt + 1, 0, ob);
#pragma unroll
                    for (int m = 0; m < 4; ++m) { ar[m][0] = ldA(rb, m, 0); ar[m][1] = ldA(rb, m, 1); }
#pragma unroll
                    for (int n = 0; n < 2; ++n) { br[n][0] = ldB(rb, n, 0); br[n][1] = ldB(rb, n, 1); }
                    BAR(); PRIO1();
                    qp(0, 0);
                    PRIO0(); SBAR0(); BAR();
                    // P2
                    stgA(tt + 1, 1, ob);
#pragma unroll
                    for (int n = 2; n < 4; ++n) { br[n][0] = ldB(rb, n, 0); br[n][1] = ldB(rb, n, 1); }
                    BAR(); PRIO1();
                    qp(0, 1);
                    PRIO0(); SBAR0(); BAR();
                    // P3
                    stgB(tt + 2, 0, rb);
#pragma unroll
                    for (int m = 0; m < 4; ++m) { ar[m][0] = ldA(rb, m + 4, 0); ar[m][1] = ldA(rb, m + 4, 1); }
                    BAR(); PRIO1();
                    qp(1, 0);
                    PRIO0(); SBAR0(); BAR();
                    // P4
                    stgB(tt + 2, 1, rb);
                    BAR(); PRIO1();
                    qp(1, 1);
                    PRIO0(); SBAR0(); VMC4(); BAR();
                }
            }

            // epilogue (plain fp32): D[row = quad*4 + r][col = fm]
#pragma unroll
            for (int i = 0; i < 8; ++i) {
                const int row0 = bm * 256 + wm * 128 + i * 16 + quad * 4;
#pragma unroll
                for (int j = 0; j < 4; ++j) {
                    const int col = bn * 256 + wn * 64 + j * 16 + fm;
#pragma unroll
                    for (int r = 0; r < 4; ++r)
                        Cfp[(long)b * sC + (long)(row0 + r) * N + col] = acc[i][j][r];
                }
            }
        }
        return;
    } else {
        // =================== 3-term hi/lo, BK=32 ===================
        auto stgAh = [&](int t, int lb) {
            const int k = (t < NT ? t : NT - 1) * BK;
            async_load16(gAh + (aof[0][0] + k), smem + lb + lof[0][0]);
            async_load16(gAh + (aof[1][0] + k), smem + lb + lof[1][0]);
        };
        auto stgAl = [&](int t, int lb) {
            const int k = (t < NT ? t : NT - 1) * BK;
            async_load16(gAl + (aof[0][0] + k), smem + lb + 16384 + lof[0][0]);
            async_load16(gAl + (aof[1][0] + k), smem + lb + 16384 + lof[1][0]);
        };
        auto stgBh = [&](int t, int lb) {
            const int k = (t < NT ? t : NT - 1) * BK;
            async_load16(gBh + (bof[0][0] + k), smem + lb + 32768 + lof[0][0]);
            async_load16(gBh + (bof[1][0] + k), smem + lb + 32768 + lof[1][0]);
        };
        auto stgBl = [&](int t, int lb) {
            const int k = (t < NT ? t : NT - 1) * BK;
            async_load16(gBl + (bof[0][0] + k), smem + lb + 49152 + lof[0][0]);
            async_load16(gBl + (bof[1][0] + k), smem + lb + 49152 + lof[1][0]);
        };
        const int xs2 = ((fm >> 1) & 3) << 4;      // read-side XOR
        auto ldSA = [&](int lb, int comp, int m) -> bf16x8 {
            const int row = wm * 128 + m * 16 + fm;
            return *(const bf16x8*)(smem + lb + comp * 16384 + row * 64 + ((quad * 16) ^ xs2));
        };
        auto ldSB = [&](int lb, int comp, int n) -> bf16x8 {
            const int row = wn * 64 + n * 16 + fm;
            return *(const bf16x8*)(smem + lb + comp * 16384 + row * 64 + ((quad * 16) ^ xs2));
        };

        bf16x8 arh[4], arl[4], brh[4], brl[4];
        auto qs = [&](int mh, int nh) {
#pragma unroll
            for (int m = 0; m < 4; ++m)
#pragma unroll
                for (int n = 0; n < 2; ++n) {
                    f32x4 c = acc[mh * 4 + m][nh * 2 + n];
                    c = __builtin_amdgcn_mfma_f32_16x16x32_bf16(arh[m], brh[nh * 2 + n], c, 0, 0, 0);
                    c = __builtin_amdgcn_mfma_f32_16x16x32_bf16(arl[m], brh[nh * 2 + n], c, 0, 0, 0);
                    c = __builtin_amdgcn_mfma_f32_16x16x32_bf16(arh[m], brl[nh * 2 + n], c, 0, 0, 0);
                    acc[mh * 4 + m][nh * 2 + n] = c;
                }
        };

        stgAh(0, 0); stgAl(0, 0); stgBh(0, 0); stgBl(0, 0);
        stgBh(1, BUF); stgBl(1, BUF);
        VMC4(); BAR();

        const int NIT = NT >> 1;
        for (int it = 0; it < NIT; ++it) {
            const int t = it << 1;
#pragma unroll
            for (int ph = 0; ph < 2; ++ph) {
                const int rb = ph ? BUF : 0;
                const int ob = ph ? 0 : BUF;
                const int tt = t + ph;
                // P1
                stgAh(tt + 1, ob);
#pragma unroll
                for (int m = 0; m < 4; ++m) { arh[m] = ldSA(rb, 0, m); arl[m] = ldSA(rb, 1, m); }
#pragma unroll
                for (int n = 0; n < 2; ++n) { brh[n] = ldSB(rb, 2, n); brl[n] = ldSB(rb, 3, n); }
                BAR(); PRIO1();
                qs(0, 0);
                PRIO0(); SBAR0(); BAR();
                // P2
                stgAl(tt + 1, ob);
#pragma unroll
                for (int n = 2; n < 4; ++n) { brh[n] = ldSB(rb, 2, n); brl[n] = ldSB(rb, 3, n); }
                BAR(); PRIO1();
                qs(0, 1);
                PRIO0(); SBAR0(); BAR();
                // P3
                stgBh(tt + 2, rb);
#pragma unroll
                for (int m = 0; m < 4; ++m) { arh[m] = ldSA(rb, 0, m + 4); arl[m] = ldSA(rb, 1, m + 4); }
                BAR(); PRIO1();
                qs(1, 0);
                PRIO0(); SBAR0(); BAR();
                // P4
                stgBl(tt + 2, rb);
                BAR(); PRIO1();
                qs(1, 1);
                PRIO0(); SBAR0(); VMC4(); BAR();
            }
        }
    }

    // ---- softmax partials from registers (STATS) ---------------------------
    // After the final vmcnt(4)+barrier the only in-flight LDS writes are the
    // 4 clamped B-stages into buf1's B region (>= BUF+32768); smem[0..12KB)
    // is safe to reuse.
    float2* colp = (float2*)smem;               // [2 wm][256 col]   4 KB
    float2* rowp = (float2*)(smem + 4096);      // [4 wn][256 row]   8 KB
    if constexpr (STATS) {
#pragma unroll
        for (int j = 0; j < 4; ++j) {           // col partials over 256 rows
            float m = acc[0][j][0];
#pragma unroll
            for (int i = 0; i < 8; ++i)
#pragma unroll
                for (int r = 0; r < 4; ++r) m = fmaxf(m, acc[i][j][r]);
            float z = 0.f;
#pragma unroll
            for (int i = 0; i < 8; ++i)
#pragma unroll
                for (int r = 0; r < 4; ++r) z += __expf(acc[i][j][r] - m);
#pragma unroll
            for (int off = 16; off <= 32; off <<= 1) {   // merge across quads
                float mo = __shfl_xor(m, off), zo = __shfl_xor(z, off);
                float nm = fmaxf(m, mo);
                z = z * __expf(m - nm) + zo * __expf(mo - nm); m = nm;
            }
            if (quad == 0) colp[wm * 256 + wn * 64 + j * 16 + fm] = make_float2(m, z);
        }
#pragma unroll
        for (int i = 0; i < 8; ++i)             // row partials over 256 cols
#pragma unroll
            for (int r = 0; r < 4; ++r) {
                float m = fmaxf(fmaxf(acc[i][0][r], acc[i][1][r]),
                                fmaxf(acc[i][2][r], acc[i][3][r]));
                float z = __expf(acc[i][0][r] - m) + __expf(acc[i][1][r] - m)
                        + __expf(acc[i][2][r] - m) + __expf(acc[i][3][r] - m);
#pragma unroll
                for (int off = 1; off <= 8; off <<= 1) { // merge across fm
                    float mo = __shfl_xor(m, off), zo = __shfl_xor(z, off);
                    float nm = fmaxf(m, mo);
                    z = z * __expf(m - nm) + zo * __expf(mo - nm); m = nm;
                }
                if (fm == 0)
                    rowp[wn * 256 + wm * 128 + i * 16 + quad * 4 + r] = make_float2(m, z);
            }
    }

    // ---- C write: D[row = quad*4 + r][col = fm] per 16x16 fragment ---------
#pragma unroll
    for (int i = 0; i < 8; ++i) {
        const int row0 = bm * 256 + wm * 128 + i * 16 + quad * 4;
#pragma unroll
        for (int j = 0; j < 4; ++j) {
            const int col = bn * 256 + wn * 64 + j * 16 + fm;
#pragma unroll
            for (int r = 0; r < 4; ++r) {
                const long idx = (long)b * sC + (long)(row0 + r) * N + col;
                const float v = acc[i][j][r];
                if constexpr (OSP) {
                    const bf16_t h = (bf16_t)v;
                    Ch[idx] = h;
                    Cl[idx] = (bf16_t)(v - (float)h);
                } else {
                    Cf[idx] = v;
                }
            }
        }
    }

    if constexpr (STATS) {
        __syncthreads();
        if (tid < 256) {                        // merge cols across wm
            float2 p0 = colp[tid], p1 = colp[256 + tid];
            float nm = fmaxf(p0.x, p1.x);
            float z = p0.y * __expf(p0.x - nm) + p1.y * __expf(p1.x - nm);
            const int gcol = bn * 256 + tid;
            Mp2[((b * 4 + bm) << 10) + gcol] = nm;
            Zp2[((b * 4 + bm) << 10) + gcol] = z;
        } else {                                // merge rows across wn
            const int rr = tid - 256;
            float2 p = rowp[rr];
            float m = p.x, z = p.y;
#pragma unroll
            for (int c = 1; c < 4; ++c) {
                float2 q = rowp[c * 256 + rr];
                float nm = fmaxf(m, q.x);
                z = z * __expf(m - nm) + q.y * __expf(q.x - nm); m = nm;
            }
            const int grow = bm * 256 + rr;
            Np2[((b * 4 + bn) << 10) + grow] = m;
            Yp2[((b * 4 + bn) << 10) + grow] = z;
        }
    }
}

// ---------------------------------------------------------------------------
// fp32 -> bf16 hi/lo split for f1 and f2, plus W transpose-split, one launch.
// Blocks [0,32768): 4 elems/thread of f1 or f2.  Blocks >=32768: one 32x32
// tile of Wt[e,d] = split(W[d,e]).
// ---------------------------------------------------------------------------
__global__ void split_all(const float* __restrict__ f1, const float* __restrict__ f2,
                          const float* __restrict__ W,
                          bf16_t* __restrict__ h1, bf16_t* __restrict__ l1,
                          bf16_t* __restrict__ h2, bf16_t* __restrict__ l2,
                          bf16_t* __restrict__ Wth, bf16_t* __restrict__ Wtl)
{
    __shared__ float tile[32][33];
    const int bid = blockIdx.x;
    if (bid < 32768) {
        const long tot = (long)B_ * MAT_;
        long i = ((long)bid * 256 + threadIdx.x) * 4;
        const float* s; bf16_t* h; bf16_t* l;
        if (i < tot) { s = f1; h = h1; l = l1; }
        else { i -= tot; s = f2; h = h2; l = l2; }
        float4 v = *(const float4*)(s + i);
        float a[4] = {v.x, v.y, v.z, v.w};
        bf16x4 hh, ll;
#pragma unroll
        for (int e = 0; e < 4; ++e) {
            const bf16_t hv = (bf16_t)a[e];
            hh[e] = hv;
            ll[e] = (bf16_t)(a[e] - (float)hv);
        }
        *(bf16x4*)(h + i) = hh;
        *(bf16x4*)(l + i) = ll;
    } else {
        const int b2 = bid - 32768;
        const int d0 = (b2 & 31) * 32, e0 = (b2 >> 5) * 32;
        const int tx = threadIdx.x & 31, ty = threadIdx.x >> 5;
        for (int r = ty; r < 32; r += 8)
            tile[r][tx] = W[(long)(d0 + r) * D_ + e0 + tx];
        __syncthreads();
        for (int r = ty; r < 32; r += 8) {
            const float v = tile[tx][r];
            const bf16_t h = (bf16_t)v;
            Wth[(long)(e0 + r) * D_ + d0 + tx] = h;
            Wtl[(long)(e0 + r) * D_ + d0 + tx] = (bf16_t)(v - (float)h);
        }
    }
}

// ---------------------------------------------------------------------------
// Fused attention-matrix build (one pass over cc), with inline 4-way
// partial-combine (replaces the separate combine kernel):
//   attV[b,s,t] = exp(cc[b,s,t]-N[b,s]) / Y[b,s]        (same layout)
//   attA[b,t,s] = exp(cc[b,s,t]-M[b,t]) / Z[b,t]        (transposed)
// ---------------------------------------------------------------------------
__global__ void build_atts(const float* __restrict__ cc,
                           const float* __restrict__ Mp2, const float* __restrict__ Zp2,
                           const float* __restrict__ Np2, const float* __restrict__ Yp2,
                           bf16_t* __restrict__ attA, bf16_t* __restrict__ attV)
{
    __shared__ float tile[32][33];
    __shared__ float tm[32], tz[32], sm[32], sz[32];
    const int b = blockIdx.z;
    const int s0 = blockIdx.x * 32, t0 = blockIdx.y * 32;
    const int tx = threadIdx.x, ty = threadIdx.y;
    const int flat = ty * 32 + tx;

    if (flat < 32) {                            // t-stats (audio: over s)
        const int t = t0 + flat;
        float m = Mp2[((b * 4) << 10) + t], z = Zp2[((b * 4) << 10) + t];
#pragma unroll
        for (int c = 1; c < 4; ++c) {
            float mc = Mp2[((b * 4 + c) << 10) + t];
            float zc = Zp2[((b * 4 + c) << 10) + t];
            float nm = fmaxf(m, mc);
            z = z * __expf(m - nm) + zc * __expf(mc - nm); m = nm;
        }
        tm[flat] = m; tz[flat] = 1.f / z;
    } else if (flat < 64) {                     // s-stats (visual: over t)
        const int ii = flat - 32;
        const int s = s0 + ii;
        float m = Np2[((b * 4) << 10) + s], z = Yp2[((b * 4) << 10) + s];
#pragma unroll
        for (int c = 1; c < 4; ++c) {
            float mc = Np2[((b * 4 + c) << 10) + s];
            float zc = Yp2[((b * 4 + c) << 10) + s];
            float nm = fmaxf(m, mc);
            z = z * __expf(m - nm) + zc * __expf(mc - nm); m = nm;
        }
        sm[ii] = m; sz[ii] = 1.f / z;
    }
    __syncthreads();

    const float* src = cc + (long)b * MAT_;
    bf16_t* dV = attV + (long)b * MAT_;
    bf16_t* dA = attA + (long)b * MAT_;
    for (int r = ty; r < 32; r += 8) {
        const int s = s0 + r;
        const float v = src[(long)s * S_ + t0 + tx];
        tile[r][tx] = v;
        dV[(long)s * S_ + t0 + tx] = (bf16_t)(__expf(v - sm[r]) * sz[r]);
    }
    __syncthreads();
    for (int r = ty; r < 32; r += 8) {
        const int t = t0 + r;
        dA[(long)t * S_ + s0 + tx] = (bf16_t)(__expf(tile[tx][r] - tm[r]) * tz[r]);
    }
}

// ---------------------------------------------------------------------------
extern "C" void kernel_launch(void* const* d_in, const int* in_sizes, int n_in,
                              void* d_out, int out_size, void* d_ws, size_t ws_size,
                              hipStream_t stream)
{
    const float* f1 = (const float*)d_in[0];   // [16,1024,1024] fp32
    const float* f2 = (const float*)d_in[1];   // [16,1024,1024] fp32
    const float* W  = (const float*)d_in[2];   // [1024,1024]    fp32

    float* out0 = (float*)d_out;               // final fp32 outputs
    float* out1 = out0 + (long)B_ * MAT_;

    // d_out reuse (regions fully dead before final overwrite):
    bf16_t* a1h = (bf16_t*)out0;               // 32 MB, dead after G2
    bf16_t* a1l = a1h + (long)B_ * MAT_;       // 32 MB, dead after G2
    bf16_t* Wth = (bf16_t*)out1;               //  2 MB, dead after G1
    bf16_t* Wtl = Wth + (long)MAT_;            //  2 MB, dead after G1
    float*  cc  = out1;                        // 64 MB fp32 logits, dead after build

    char* w = (char*)d_ws;                     // total ws use: ~129 MB
    bf16_t* f1h  = (bf16_t*)(w);               // 32 MB  (G1, G56)
    bf16_t* f2h  = (bf16_t*)(w + (32l << 20)); // 32 MB  (G2, G56)
    bf16_t* f1l  = (bf16_t*)(w + (64l << 20)); // 32 MB  (G1 only)
    bf16_t* f2l  = (bf16_t*)(w + (96l << 20)); // 32 MB  (G2 only)
    bf16_t* attA = f1l;                        // aliases f1l (dead after G1)
    bf16_t* attV = f2l;                        // aliases f2l (dead after G2)
    float*  Mp2  = (float*)(w + (128l << 20)); // [16][4][1024] partials
    float*  Zp2  = Mp2 + 16 * 4 * 1024;
    float*  Np2  = Zp2 + 16 * 4 * 1024;
    float*  Yp2  = Np2 + 16 * 4 * 1024;        // 1 MB total

    // 0. pre-split all fp32 operands to bf16 hi/lo + W transpose (one launch)
    split_all<<<33792, 256, 0, stream>>>(f1, f2, W, f1h, f1l, f2h, f2l, Wth, Wtl);

    // 1. a1 = f1 @ Wt^T (3-term split), bf16 hi/lo; bm-contiguous per XCD
    gemm8p<1, 1, 3, 0><<<dim3(4, 64, 1), 512, 0, stream>>>(
        f1h, f1l, Wth, Wtl, nullptr, a1h, a1l,
        nullptr, nullptr, nullptr, nullptr, BS_, 1024, 1024, 0, 0, 0);

    // 2. cc[b] = a1[b] @ f2[b]^T (3-term split) + in-epilogue softmax partials
    gemm8p<1, 0, 1, 1><<<dim3(4, 4, 16), 512, 0, stream>>>(
        a1h, a1l, f2h, f2l, cc, nullptr, nullptr,
        Mp2, Zp2, Np2, Yp2, 1024, 1024, 1024, MAT_, MAT_, MAT_);

    // 3. fused combine + attention-matrix build (one cc pass)
    build_atts<<<dim3(32, 32, 16), dim3(32, 8), 0, stream>>>(
        cc, Mp2, Zp2, Np2, Yp2, attA, attV);

    // 4. paired: out0[b] = attA^T[b] @ f1[b]^T ; out1[b] = attV^T[b] @ f2[b]^T
    //    256 blocks, each runs both GEMMs back-to-back (no block restart).
    gemm8p<0, 0, 2, 0><<<dim3(4, 4, 16), 512, 0, stream>>>(
        attA, attV, f1h, f2h, out0, nullptr, nullptr,
        nullptr, nullptr, nullptr, nullptr, 1024, 1024, 1024, MAT_, MAT_, MAT_);
}

// Round 4
// 498.470 us; speedup vs baseline: 1.0695x; 1.0695x over previous
//
#include <hip/hip_runtime.h>
#include <hip/hip_bf16.h>
#include <stdint.h>

typedef __bf16 bf16_t;
typedef bf16_t bf16x8 __attribute__((ext_vector_type(8)));
typedef bf16_t bf16x4 __attribute__((ext_vector_type(4)));
typedef float  f32x4  __attribute__((ext_vector_type(4)));

#define B_  16
#define S_  1024
#define D_  1024
#define BS_ (B_ * S_)            // 16384
#define MAT_ (S_ * D_)           // 1048576 elems per batch matrix

#define BAR()   __builtin_amdgcn_s_barrier()
#define LGKM0() asm volatile("s_waitcnt lgkmcnt(0)" ::: "memory")
#define VMC4()  asm volatile("s_waitcnt vmcnt(4)" ::: "memory")

__device__ __forceinline__ void async_load16(const void* g, void* l) {
    __builtin_amdgcn_global_load_lds((__attribute__((address_space(1))) void*)(g),
                                     (__attribute__((address_space(3))) void*)(l),
                                     16, 0, 0);
}

// ---------------------------------------------------------------------------
// 256x256 8-phase pipelined GEMM (HK/m201 schedule in plain HIP).
// C[m,n] = sum_k A[m,k]*B[n,k]   (B given K-contiguous / transposed)
// SPLIT=0: plain bf16, BK=64, (row&7)<<4 LDS XOR-swizzle (conflict-free).
// SPLIT=1: 3-term Markidis hi/lo bf16, BK=32, ((row>>1)&3)<<4 swizzle.
// OSP=1: C written as bf16 hi/lo pair.
// XS=1: batch-per-XCD remap, grid (4,4,16).
// XS=2: DUAL mode, grid (4,4,32): b<16 -> (gAh,gBh)->Cf; b>=16 -> (gAl,gBl)
//       ->Cf+16*MAT_.  4 batches per XCD.  (128 KiB LDS => 1 block/CU; the
//       two GEMMs overlap via block turnover, NOT via pairing inside a
//       block — pairing serializes on the C-store vmcnt drain; measured
//       −16% in round 3.)
// XS=3: G1 mode, grid (4,64,1): 8 contiguous bm per XCD (A-panel L2 reuse).
// STATS=1: epilogue emits per-block softmax partials for both axes.
//
// Inner-loop schedule is the round-2 measured-good config (MfmaUtil 43-44%,
// 0 bank conflicts): reads -> stage -> BAR -> lgkmcnt(0) -> setprio(1) MFMA
// setprio(0) -> BAR; counted vmcnt(4) at phases 4/8 only (2 loads/half-tile,
// 2 half-tiles in flight).  Tail stage indices clamp to NT-1 so the vmcnt
// accounting stays exact.  Swizzle is both-sides (rule 21): linear LDS dest,
// pre-permuted global source chunk, XOR'd ds_read address (same involution).
// ---------------------------------------------------------------------------
template <int SPLIT, int OSP, int XS, int STATS>
__global__ __launch_bounds__(512, 2)
void gemm8p(const bf16_t* __restrict__ gAh, const bf16_t* __restrict__ gAl,
            const bf16_t* __restrict__ gBh, const bf16_t* __restrict__ gBl,
            float* __restrict__ Cf, bf16_t* __restrict__ Ch, bf16_t* __restrict__ Cl,
            float* __restrict__ Mp2, float* __restrict__ Zp2,
            float* __restrict__ Np2, float* __restrict__ Yp2,
            int M, int N, int K, long sA, long sB, long sC)
{
    (void)M;
    constexpr int BK  = SPLIT ? 32 : 64;
    constexpr int BUF = 65536;
    __shared__ __attribute__((aligned(16))) char smem[2 * BUF];   // 128 KiB

    const int tid  = threadIdx.x;
    const int w    = tid >> 6;
    const int lane = tid & 63;
    const int wm   = w >> 2;            // 0..1  (row half)
    const int wn   = w & 3;             // 0..3  (col quarter)
    const int fm   = lane & 15;
    const int quad = lane >> 4;

    int bm, bn, b;
    if constexpr (XS == 1) {
        // batch-per-XCD: XCD k owns batches {2k,2k+1} (bijective on 4x4x16)
        const int flat = (int)blockIdx.x + ((int)blockIdx.y << 2) + ((int)blockIdx.z << 4);
        const int xcd = flat & 7, slot = flat >> 3;
        b  = (xcd << 1) | (slot >> 4);
        bm = (slot >> 2) & 3;
        bn = slot & 3;
    } else if constexpr (XS == 2) {
        // dual: 512 blocks, XCD k owns batches {4k..4k+3}
        const int flat = (int)blockIdx.x + ((int)blockIdx.y << 2) + ((int)blockIdx.z << 4);
        const int xcd = flat & 7, slot = flat >> 3;      // slot in [0,64)
        b  = (xcd << 2) | (slot >> 4);
        bm = (slot >> 2) & 3;
        bn = slot & 3;
    } else if constexpr (XS == 3) {
        // grid (4,64,1): XCD k owns bm in [8k,8k+8) (A-panel reuse in L2)
        const int flat = (int)blockIdx.x + ((int)blockIdx.y << 2);
        const int xcd = flat & 7, slot = flat >> 3;      // slot in [0,32)
        b  = 0;
        bm = (xcd << 3) | (slot >> 2);
        bn = slot & 3;
    } else {
        bn = blockIdx.x; bm = blockIdx.y; b = blockIdx.z;
    }

    // operand select (DUAL)
    const bf16_t* pAh = gAh; const bf16_t* pAl = gAl;
    const bf16_t* pBh = gBh; const bf16_t* pBl = gBl;
    float* Cfp = Cf;
    if constexpr (XS == 2) {
        if (b >= 16) { pAh = gAl; pBh = gBl; Cfp = Cf + (long)B_ * MAT_; b -= 16; }
    }

    const int NT    = K / BK;
    const int abase = (int)((long)b * sA) + bm * 256 * K;
    const int bbase = (int)((long)b * sB) + bn * 256 * K;

    // ---- per-thread stage offsets (global elem offset sans k; lds byte) ----
    int aof[2][2], bof[2][2], lof[2][2];
    if constexpr (!SPLIT) {
        // component tile [256][64] bf16 (128B rows). Linear LDS dest o;
        // source 16B-chunk permuted by (row&7) so read-side XOR matches.
#pragma unroll
        for (int h = 0; h < 2; ++h)
#pragma unroll
            for (int i = 0; i < 2; ++i) {
                const int o   = h * 16384 + i * 8192 + tid * 16;
                const int row = o >> 7;
                const int c   = ((o >> 4) & 7) ^ (row & 7);
                aof[h][i] = abase + row * K + c * 8;
                bof[h][i] = bbase + row * K + c * 8;
                lof[h][i] = o;
            }
    } else {
        // component tile [256][32] bf16 (64B rows): chunk ^= (row>>1)&3.
#pragma unroll
        for (int h = 0; h < 2; ++h) {
            const int o   = h * 8192 + tid * 16;
            const int row = o >> 6;
            const int c   = ((o >> 4) & 3) ^ ((row >> 1) & 3);
            aof[h][0] = abase + row * K + c * 8;
            bof[h][0] = bbase + row * K + c * 8;
            lof[h][0] = o;
        }
    }

    f32x4 acc[8][4] = {};

    if constexpr (!SPLIT) {
        // =================== plain bf16, BK=64 ===================
        auto stgA = [&](int t, int h, int lb) {
            const int k = (t < NT ? t : NT - 1) * BK;
            async_load16(pAh + (aof[h][0] + k), smem + lb + lof[h][0]);
            async_load16(pAh + (aof[h][1] + k), smem + lb + lof[h][1]);
        };
        auto stgB = [&](int t, int h, int lb) {
            const int k = (t < NT ? t : NT - 1) * BK;
            async_load16(pBh + (bof[h][0] + k), smem + lb + 32768 + lof[h][0]);
            async_load16(pBh + (bof[h][1] + k), smem + lb + 32768 + lof[h][1]);
        };
        const int xb = (fm & 7) << 4;              // read-side XOR = (row&7)<<4
        auto ldA = [&](int lb, int m, int ks) -> bf16x8 {
            const int row = wm * 128 + m * 16 + fm;
            return *(const bf16x8*)(smem + lb + row * 128 + ((ks * 64 + quad * 16) ^ xb));
        };
        auto ldB = [&](int lb, int n, int ks) -> bf16x8 {
            const int row = wn * 64 + n * 16 + fm;
            return *(const bf16x8*)(smem + lb + 32768 + row * 128 + ((ks * 64 + quad * 16) ^ xb));
        };

        bf16x8 ar[4][2], br[4][2];
        auto qp = [&](int mh, int nh) {
#pragma unroll
            for (int m = 0; m < 4; ++m)
#pragma unroll
                for (int n = 0; n < 2; ++n) {
                    f32x4 c = acc[mh * 4 + m][nh * 2 + n];
                    c = __builtin_amdgcn_mfma_f32_16x16x32_bf16(ar[m][0], br[nh * 2 + n][0], c, 0, 0, 0);
                    c = __builtin_amdgcn_mfma_f32_16x16x32_bf16(ar[m][1], br[nh * 2 + n][1], c, 0, 0, 0);
                    acc[mh * 4 + m][nh * 2 + n] = c;
                }
        };

        stgA(0, 0, 0); stgA(0, 1, 0); stgB(0, 0, 0); stgB(0, 1, 0);
        stgB(1, 0, BUF); stgB(1, 1, BUF);
        VMC4(); BAR();

        const int NIT = NT >> 1;
        for (int it = 0; it < NIT; ++it) {
            const int t = it << 1;
#pragma unroll
            for (int ph = 0; ph < 2; ++ph) {
                const int rb = ph ? BUF : 0;
                const int ob = ph ? 0 : BUF;
                const int tt = t + ph;
                // P1
#pragma unroll
                for (int m = 0; m < 4; ++m) { ar[m][0] = ldA(rb, m, 0); ar[m][1] = ldA(rb, m, 1); }
#pragma unroll
                for (int n = 0; n < 2; ++n) { br[n][0] = ldB(rb, n, 0); br[n][1] = ldB(rb, n, 1); }
                stgA(tt + 1, 0, ob);
                BAR(); LGKM0(); __builtin_amdgcn_s_setprio(1);
                qp(0, 0);
                __builtin_amdgcn_s_setprio(0); BAR();
                // P2
#pragma unroll
                for (int n = 2; n < 4; ++n) { br[n][0] = ldB(rb, n, 0); br[n][1] = ldB(rb, n, 1); }
                stgA(tt + 1, 1, ob);
                BAR(); LGKM0(); __builtin_amdgcn_s_setprio(1);
                qp(0, 1);
                __builtin_amdgcn_s_setprio(0); BAR();
                // P3
#pragma unroll
                for (int m = 0; m < 4; ++m) { ar[m][0] = ldA(rb, m + 4, 0); ar[m][1] = ldA(rb, m + 4, 1); }
                stgB(tt + 2, 0, rb);
                BAR(); LGKM0(); __builtin_amdgcn_s_setprio(1);
                qp(1, 0);
                __builtin_amdgcn_s_setprio(0); BAR();
                // P4
                stgB(tt + 2, 1, rb);
                BAR(); LGKM0(); __builtin_amdgcn_s_setprio(1);
                qp(1, 1);
                __builtin_amdgcn_s_setprio(0); VMC4(); BAR();
            }
        }
    } else {
        // =================== 3-term hi/lo, BK=32 ===================
        auto stgAh = [&](int t, int lb) {
            const int k = (t < NT ? t : NT - 1) * BK;
            async_load16(pAh + (aof[0][0] + k), smem + lb + lof[0][0]);
            async_load16(pAh + (aof[1][0] + k), smem + lb + lof[1][0]);
        };
        auto stgAl = [&](int t, int lb) {
            const int k = (t < NT ? t : NT - 1) * BK;
            async_load16(pAl + (aof[0][0] + k), smem + lb + 16384 + lof[0][0]);
            async_load16(pAl + (aof[1][0] + k), smem + lb + 16384 + lof[1][0]);
        };
        auto stgBh = [&](int t, int lb) {
            const int k = (t < NT ? t : NT - 1) * BK;
            async_load16(pBh + (bof[0][0] + k), smem + lb + 32768 + lof[0][0]);
            async_load16(pBh + (bof[1][0] + k), smem + lb + 32768 + lof[1][0]);
        };
        auto stgBl = [&](int t, int lb) {
            const int k = (t < NT ? t : NT - 1) * BK;
            async_load16(pBl + (bof[0][0] + k), smem + lb + 49152 + lof[0][0]);
            async_load16(pBl + (bof[1][0] + k), smem + lb + 49152 + lof[1][0]);
        };
        const int xs2 = ((fm >> 1) & 3) << 4;      // read-side XOR
        auto ldSA = [&](int lb, int comp, int m) -> bf16x8 {
            const int row = wm * 128 + m * 16 + fm;
            return *(const bf16x8*)(smem + lb + comp * 16384 + row * 64 + ((quad * 16) ^ xs2));
        };
        auto ldSB = [&](int lb, int comp, int n) -> bf16x8 {
            const int row = wn * 64 + n * 16 + fm;
            return *(const bf16x8*)(smem + lb + comp * 16384 + row * 64 + ((quad * 16) ^ xs2));
        };

        bf16x8 arh[4], arl[4], brh[4], brl[4];
        auto qs = [&](int mh, int nh) {
#pragma unroll
            for (int m = 0; m < 4; ++m)
#pragma unroll
                for (int n = 0; n < 2; ++n) {
                    f32x4 c = acc[mh * 4 + m][nh * 2 + n];
                    c = __builtin_amdgcn_mfma_f32_16x16x32_bf16(arh[m], brh[nh * 2 + n], c, 0, 0, 0);
                    c = __builtin_amdgcn_mfma_f32_16x16x32_bf16(arl[m], brh[nh * 2 + n], c, 0, 0, 0);
                    c = __builtin_amdgcn_mfma_f32_16x16x32_bf16(arh[m], brl[nh * 2 + n], c, 0, 0, 0);
                    acc[mh * 4 + m][nh * 2 + n] = c;
                }
        };

        stgAh(0, 0); stgAl(0, 0); stgBh(0, 0); stgBl(0, 0);
        stgBh(1, BUF); stgBl(1, BUF);
        VMC4(); BAR();

        const int NIT = NT >> 1;
        for (int it = 0; it < NIT; ++it) {
            const int t = it << 1;
#pragma unroll
            for (int ph = 0; ph < 2; ++ph) {
                const int rb = ph ? BUF : 0;
                const int ob = ph ? 0 : BUF;
                const int tt = t + ph;
                // P1
#pragma unroll
                for (int m = 0; m < 4; ++m) { arh[m] = ldSA(rb, 0, m); arl[m] = ldSA(rb, 1, m); }
#pragma unroll
                for (int n = 0; n < 2; ++n) { brh[n] = ldSB(rb, 2, n); brl[n] = ldSB(rb, 3, n); }
                stgAh(tt + 1, ob);
                BAR(); LGKM0(); __builtin_amdgcn_s_setprio(1);
                qs(0, 0);
                __builtin_amdgcn_s_setprio(0); BAR();
                // P2
#pragma unroll
                for (int n = 2; n < 4; ++n) { brh[n] = ldSB(rb, 2, n); brl[n] = ldSB(rb, 3, n); }
                stgAl(tt + 1, ob);
                BAR(); LGKM0(); __builtin_amdgcn_s_setprio(1);
                qs(0, 1);
                __builtin_amdgcn_s_setprio(0); BAR();
                // P3
#pragma unroll
                for (int m = 0; m < 4; ++m) { arh[m] = ldSA(rb, 0, m + 4); arl[m] = ldSA(rb, 1, m + 4); }
                stgBh(tt + 2, rb);
                BAR(); LGKM0(); __builtin_amdgcn_s_setprio(1);
                qs(1, 0);
                __builtin_amdgcn_s_setprio(0); BAR();
                // P4
                stgBl(tt + 2, rb);
                BAR(); LGKM0(); __builtin_amdgcn_s_setprio(1);
                qs(1, 1);
                __builtin_amdgcn_s_setprio(0); VMC4(); BAR();
            }
        }
    }

    // ---- softmax partials from registers (STATS) ---------------------------
    // After the final vmcnt(4)+barrier the only in-flight LDS writes are the
    // 4 clamped B-stages into buf1's B region (>= BUF+32768); smem[0..12KB)
    // is safe to reuse.
    float2* colp = (float2*)smem;               // [2 wm][256 col]   4 KB
    float2* rowp = (float2*)(smem + 4096);      // [4 wn][256 row]   8 KB
    if constexpr (STATS) {
#pragma unroll
        for (int j = 0; j < 4; ++j) {           // col partials over 256 rows
            float m = acc[0][j][0];
#pragma unroll
            for (int i = 0; i < 8; ++i)
#pragma unroll
                for (int r = 0; r < 4; ++r) m = fmaxf(m, acc[i][j][r]);
            float z = 0.f;
#pragma unroll
            for (int i = 0; i < 8; ++i)
#pragma unroll
                for (int r = 0; r < 4; ++r) z += __expf(acc[i][j][r] - m);
#pragma unroll
            for (int off = 16; off <= 32; off <<= 1) {   // merge across quads
                float mo = __shfl_xor(m, off), zo = __shfl_xor(z, off);
                float nm = fmaxf(m, mo);
                z = z * __expf(m - nm) + zo * __expf(mo - nm); m = nm;
            }
            if (quad == 0) colp[wm * 256 + wn * 64 + j * 16 + fm] = make_float2(m, z);
        }
#pragma unroll
        for (int i = 0; i < 8; ++i)             // row partials over 256 cols
#pragma unroll
            for (int r = 0; r < 4; ++r) {
                float m = fmaxf(fmaxf(acc[i][0][r], acc[i][1][r]),
                                fmaxf(acc[i][2][r], acc[i][3][r]));
                float z = __expf(acc[i][0][r] - m) + __expf(acc[i][1][r] - m)
                        + __expf(acc[i][2][r] - m) + __expf(acc[i][3][r] - m);
#pragma unroll
                for (int off = 1; off <= 8; off <<= 1) { // merge across fm
                    float mo = __shfl_xor(m, off), zo = __shfl_xor(z, off);
                    float nm = fmaxf(m, mo);
                    z = z * __expf(m - nm) + zo * __expf(mo - nm); m = nm;
                }
                if (fm == 0)
                    rowp[wn * 256 + wm * 128 + i * 16 + quad * 4 + r] = make_float2(m, z);
            }
    }

    // ---- C write: D[row = quad*4 + r][col = fm] per 16x16 fragment ---------
#pragma unroll
    for (int i = 0; i < 8; ++i) {
        const int row0 = bm * 256 + wm * 128 + i * 16 + quad * 4;
#pragma unroll
        for (int j = 0; j < 4; ++j) {
            const int col = bn * 256 + wn * 64 + j * 16 + fm;
#pragma unroll
            for (int r = 0; r < 4; ++r) {
                const long idx = (long)b * sC + (long)(row0 + r) * N + col;
                const float v = acc[i][j][r];
                if constexpr (OSP) {
                    const bf16_t h = (bf16_t)v;
                    Ch[idx] = h;
                    Cl[idx] = (bf16_t)(v - (float)h);
                } else {
                    Cfp[idx] = v;
                }
            }
        }
    }

    if constexpr (STATS) {
        __syncthreads();
        if (tid < 256) {                        // merge cols across wm
            float2 p0 = colp[tid], p1 = colp[256 + tid];
            float nm = fmaxf(p0.x, p1.x);
            float z = p0.y * __expf(p0.x - nm) + p1.y * __expf(p1.x - nm);
            const int gcol = bn * 256 + tid;
            Mp2[((b * 4 + bm) << 10) + gcol] = nm;
            Zp2[((b * 4 + bm) << 10) + gcol] = z;
        } else {                                // merge rows across wn
            const int rr = tid - 256;
            float2 p = rowp[rr];
            float m = p.x, z = p.y;
#pragma unroll
            for (int c = 1; c < 4; ++c) {
                float2 q = rowp[c * 256 + rr];
                float nm = fmaxf(m, q.x);
                z = z * __expf(m - nm) + q.y * __expf(q.x - nm); m = nm;
            }
            const int grow = bm * 256 + rr;
            Np2[((b * 4 + bn) << 10) + grow] = m;
            Yp2[((b * 4 + bn) << 10) + grow] = z;
        }
    }
}

// ---------------------------------------------------------------------------
// fp32 -> bf16 hi/lo split for f1 and f2, plus W transpose-split, one launch.
// Blocks [0,32768): 4 elems/thread of f1 or f2.  Blocks >=32768: one 32x32
// tile of Wt[e,d] = split(W[d,e]).
// ---------------------------------------------------------------------------
__global__ void split_all(const float* __restrict__ f1, const float* __restrict__ f2,
                          const float* __restrict__ W,
                          bf16_t* __restrict__ h1, bf16_t* __restrict__ l1,
                          bf16_t* __restrict__ h2, bf16_t* __restrict__ l2,
                          bf16_t* __restrict__ Wth, bf16_t* __restrict__ Wtl)
{
    __shared__ float tile[32][33];
    const int bid = blockIdx.x;
    if (bid < 32768) {
        const long tot = (long)B_ * MAT_;
        long i = ((long)bid * 256 + threadIdx.x) * 4;
        const float* s; bf16_t* h; bf16_t* l;
        if (i < tot) { s = f1; h = h1; l = l1; }
        else { i -= tot; s = f2; h = h2; l = l2; }
        float4 v = *(const float4*)(s + i);
        float a[4] = {v.x, v.y, v.z, v.w};
        bf16x4 hh, ll;
#pragma unroll
        for (int e = 0; e < 4; ++e) {
            const bf16_t hv = (bf16_t)a[e];
            hh[e] = hv;
            ll[e] = (bf16_t)(a[e] - (float)hv);
        }
        *(bf16x4*)(h + i) = hh;
        *(bf16x4*)(l + i) = ll;
    } else {
        const int b2 = bid - 32768;
        const int d0 = (b2 & 31) * 32, e0 = (b2 >> 5) * 32;
        const int tx = threadIdx.x & 31, ty = threadIdx.x >> 5;
        for (int r = ty; r < 32; r += 8)
            tile[r][tx] = W[(long)(d0 + r) * D_ + e0 + tx];
        __syncthreads();
        for (int r = ty; r < 32; r += 8) {
            const float v = tile[tx][r];
            const bf16_t h = (bf16_t)v;
            Wth[(long)(e0 + r) * D_ + d0 + tx] = h;
            Wtl[(long)(e0 + r) * D_ + d0 + tx] = (bf16_t)(v - (float)h);
        }
    }
}

// ---------------------------------------------------------------------------
// Fused attention-matrix build (one pass over cc), with inline 4-way
// partial-combine:
//   attV[b,s,t] = exp(cc[b,s,t]-N[b,s]) / Y[b,s]        (same layout)
//   attA[b,t,s] = exp(cc[b,s,t]-M[b,t]) / Z[b,t]        (transposed)
// ---------------------------------------------------------------------------
__global__ void build_atts(const float* __restrict__ cc,
                           const float* __restrict__ Mp2, const float* __restrict__ Zp2,
                           const float* __restrict__ Np2, const float* __restrict__ Yp2,
                           bf16_t* __restrict__ attA, bf16_t* __restrict__ attV)
{
    __shared__ float tile[32][33];
    __shared__ float tm[32], tz[32], sm[32], sz[32];
    const int b = blockIdx.z;
    const int s0 = blockIdx.x * 32, t0 = blockIdx.y * 32;
    const int tx = threadIdx.x, ty = threadIdx.y;
    const int flat = ty * 32 + tx;

    if (flat < 32) {                            // t-stats (audio: over s)
        const int t = t0 + flat;
        float m = Mp2[((b * 4) << 10) + t], z = Zp2[((b * 4) << 10) + t];
#pragma unroll
        for (int c = 1; c < 4; ++c) {
            float mc = Mp2[((b * 4 + c) << 10) + t];
            float zc = Zp2[((b * 4 + c) << 10) + t];
            float nm = fmaxf(m, mc);
            z = z * __expf(m - nm) + zc * __expf(mc - nm); m = nm;
        }
        tm[flat] = m; tz[flat] = 1.f / z;
    } else if (flat < 64) {                     // s-stats (visual: over t)
        const int ii = flat - 32;
        const int s = s0 + ii;
        float m = Np2[((b * 4) << 10) + s], z = Yp2[((b * 4) << 10) + s];
#pragma unroll
        for (int c = 1; c < 4; ++c) {
            float mc = Np2[((b * 4 + c) << 10) + s];
            float zc = Yp2[((b * 4 + c) << 10) + s];
            float nm = fmaxf(m, mc);
            z = z * __expf(m - nm) + zc * __expf(mc - nm); m = nm;
        }
        sm[ii] = m; sz[ii] = 1.f / z;
    }
    __syncthreads();

    const float* src = cc + (long)b * MAT_;
    bf16_t* dV = attV + (long)b * MAT_;
    bf16_t* dA = attA + (long)b * MAT_;
    for (int r = ty; r < 32; r += 8) {
        const int s = s0 + r;
        const float v = src[(long)s * S_ + t0 + tx];
        tile[r][tx] = v;
        dV[(long)s * S_ + t0 + tx] = (bf16_t)(__expf(v - sm[r]) * sz[r]);
    }
    __syncthreads();
    for (int r = ty; r < 32; r += 8) {
        const int t = t0 + r;
        dA[(long)t * S_ + s0 + tx] = (bf16_t)(__expf(tile[tx][r] - tm[r]) * tz[r]);
    }
}

// ---------------------------------------------------------------------------
extern "C" void kernel_launch(void* const* d_in, const int* in_sizes, int n_in,
                              void* d_out, int out_size, void* d_ws, size_t ws_size,
                              hipStream_t stream)
{
    const float* f1 = (const float*)d_in[0];   // [16,1024,1024] fp32
    const float* f2 = (const float*)d_in[1];   // [16,1024,1024] fp32
    const float* W  = (const float*)d_in[2];   // [1024,1024]    fp32

    float* out0 = (float*)d_out;               // final fp32 outputs
    float* out1 = out0 + (long)B_ * MAT_;

    // d_out reuse (regions fully dead before final overwrite):
    bf16_t* a1h = (bf16_t*)out0;               // 32 MB, dead after G2
    bf16_t* a1l = a1h + (long)B_ * MAT_;       // 32 MB, dead after G2
    bf16_t* Wth = (bf16_t*)out1;               //  2 MB, dead after G1
    bf16_t* Wtl = Wth + (long)MAT_;            //  2 MB, dead after G1
    float*  cc  = out1;                        // 64 MB fp32 logits, dead after build

    char* w = (char*)d_ws;                     // total ws use: ~129 MB
    bf16_t* f1h  = (bf16_t*)(w);               // 32 MB  (G1, G56)
    bf16_t* f2h  = (bf16_t*)(w + (32l << 20)); // 32 MB  (G2, G56)
    bf16_t* f1l  = (bf16_t*)(w + (64l << 20)); // 32 MB  (G1 only)
    bf16_t* f2l  = (bf16_t*)(w + (96l << 20)); // 32 MB  (G2 only)
    bf16_t* attA = f1l;                        // aliases f1l (dead after G1)
    bf16_t* attV = f2l;                        // aliases f2l (dead after G2)
    float*  Mp2  = (float*)(w + (128l << 20)); // [16][4][1024] partials
    float*  Zp2  = Mp2 + 16 * 4 * 1024;
    float*  Np2  = Zp2 + 16 * 4 * 1024;
    float*  Yp2  = Np2 + 16 * 4 * 1024;        // 1 MB total

    // 0. pre-split all fp32 operands to bf16 hi/lo + W transpose (one launch)
    split_all<<<33792, 256, 0, stream>>>(f1, f2, W, f1h, f1l, f2h, f2l, Wth, Wtl);

    // 1. a1 = f1 @ Wt^T (3-term split), bf16 hi/lo; bm-contiguous per XCD
    gemm8p<1, 1, 3, 0><<<dim3(4, 64, 1), 512, 0, stream>>>(
        f1h, f1l, Wth, Wtl, nullptr, a1h, a1l,
        nullptr, nullptr, nullptr, nullptr, BS_, 1024, 1024, 0, 0, 0);

    // 2. cc[b] = a1[b] @ f2[b]^T (3-term split) + in-epilogue softmax partials
    gemm8p<1, 0, 1, 1><<<dim3(4, 4, 16), 512, 0, stream>>>(
        a1h, a1l, f2h, f2l, cc, nullptr, nullptr,
        Mp2, Zp2, Np2, Yp2, 1024, 1024, 1024, MAT_, MAT_, MAT_);

    // 3. fused combine + attention-matrix build (one cc pass)
    build_atts<<<dim3(32, 32, 16), dim3(32, 8), 0, stream>>>(
        cc, Mp2, Zp2, Np2, Yp2, attA, attV);

    // 4. dual: out0[b] = attA^T[b] @ f1[b]^T ; out1[b] = attV^T[b] @ f2[b]^T
    //    512-block dispatch; block turnover overlaps store tails with compute.
    gemm8p<0, 0, 2, 0><<<dim3(4, 4, 32), 512, 0, stream>>>(
        attA, attV, f1h, f2h, out0, nullptr, nullptr,
        nullptr, nullptr, nullptr, nullptr, 1024, 1024, 1024, MAT_, MAT_, MAT_);
}